// Round 1
// baseline (245.770 us; speedup 1.0000x reference)
//
#include <hip/hip_runtime.h>
#include <math.h>

#define NA 49152      // 64*64*12 anchors
#define NB 16
#define ABLOCKS 192   // NA / 256

__constant__ float RP[21][2] = {
  {213.33335876464844f, 124.50563049316406f},
  {190.504638671875f,   115.11840057373047f},
  {169.9791717529297f,  101.77180480957031f},
  {146.72341918945312f, 96.25749206542969f},
  {128.86770629882812f, 87.2344970703125f},
  {150.34292602539062f, 101.61070251464844f},
  {119.29926300048828f, 98.73982238769531f},
  {100.03463745117188f, 99.74459838867188f},
  {82.62400817871094f,  101.2509536743164f},
  {148.91049194335938f, 112.71517181396484f},
  {114.37303161621094f, 113.20121002197266f},
  {91.90096282958984f,  116.49812316894531f},
  {74.75020599365234f,  119.37875366210938f},
  {149.59658813476562f, 124.09295654296875f},
  {119.72419738769531f, 126.36898040771484f},
  {99.59107208251953f,  129.40196228027344f},
  {82.82524108886719f,  131.584228515625f},
  {154.55911254882812f, 135.07681274414062f},
  {133.8833770751953f,  140.85983276367188f},
  {120.45906066894531f, 145.40306091308594f},
  {106.21541595458984f, 150.072265625f}
};

// numpy pairwise-sum (n=21) replica for REF_POSE.mean(axis=0)
__device__ __forceinline__ void ref_center(float& cx, float& cy) {
  #pragma clang fp contract(off)
  float rx[8], ry[8];
  #pragma unroll
  for (int j = 0; j < 8; ++j) {
    rx[j] = RP[j][0] + RP[j + 8][0];
    ry[j] = RP[j][1] + RP[j + 8][1];
  }
  float sx = ((rx[0] + rx[1]) + (rx[2] + rx[3])) + ((rx[4] + rx[5]) + (rx[6] + rx[7]));
  float sy = ((ry[0] + ry[1]) + (ry[2] + ry[3])) + ((ry[4] + ry[5]) + (ry[6] + ry[7]));
  #pragma unroll
  for (int j = 16; j < 21; ++j) { sx += RP[j][0]; sy += RP[j][1]; }
  cx = sx / 21.0f;
  cy = sy / 21.0f;
}

// base pose point p (scale*4 + orient), keypoint j, plus grid shift.
// Rotations by 0/90/180/270 are exactly negate/swap under f32 (the ~6e-17
// cos terms are below ulp/2 of every operand in REF_POSE-c).
__device__ __forceinline__ float2 anchor_pt(int p, int j, float cx, float cy,
                                            float shx, float shy) {
  #pragma clang fp contract(off)
  const int si = p >> 2, oi = p & 3;
  const float s = (si == 0) ? 0.25f : (si == 1 ? 0.5f : 1.0f);
  const float dx = s * (RP[j][0] - cx);
  const float dy = s * (RP[j][1] - cy);
  const float rx = (oi == 0) ? dx : (oi == 1 ? -dy : (oi == 2 ? -dx : dy));
  const float ry = (oi == 0) ? dy : (oi == 1 ? dx : (oi == 2 ? -dy : -dx));
  return make_float2((cx + rx) + shx, (cy + ry) + shy);
}

__global__ __launch_bounds__(256) void k_anchors(float* __restrict__ oa,
                                                 float* __restrict__ oinside) {
  #pragma clang fp contract(off)
  const int a = blockIdx.x * 256 + threadIdx.x;
  float cx, cy; ref_center(cx, cy);
  const int p = a % 12;
  const int kc = a / 12;
  const float shx = 4.0f * (float)(kc & 63);
  const float shy = 4.0f * (float)(kc >> 6);
  bool inside = true;
  float2* outp = reinterpret_cast<float2*>(oa) + (size_t)a * 21;
  #pragma unroll
  for (int j = 0; j < 21; ++j) {
    float2 an = anchor_pt(p, j, cx, cy, shx, shy);
    inside = inside && (an.x >= 0.0f) && (an.y >= 0.0f) &&
                       (an.x < 256.0f) && (an.y < 256.0f);
    outp[j] = an;
  }
  oinside[a] = inside ? 1.0f : 0.0f;
}

// one OKS term: exp computed in double -> rounded to f32 (~correctly rounded)
#define OKS_TERM(h, j, axv, ayv, tvar) do {                                  \
    float dxx = (axv) - sgt[(h)*63 + (j)*3];                                 \
    float dyy = (ayv) - sgt[(h)*63 + (j)*3 + 1];                             \
    float d2 = dxx*dxx + dyy*dyy;                                            \
    float vis = (sgt[(h)*63 + (j)*3 + 2] > 0.0f) ? 1.0f : 0.0f;              \
    tvar = (float)::exp((double)(-d2 / sden[h])) * vis;                      \
  } while (0)

__global__ __launch_bounds__(256) void k_targets(const float* __restrict__ gt,
                                                 const int* __restrict__ ht,
                                                 float* __restrict__ ol,
                                                 float* __restrict__ oo) {
  #pragma clang fp contract(off)
  __shared__ float sgt[126];
  __shared__ float sden[2];
  __shared__ float snv[2];
  __shared__ int sht[2];
  const int tid = threadIdx.x;
  const int b = blockIdx.x / ABLOCKS;
  const int ab = blockIdx.x % ABLOCKS;

  if (tid < 126) sgt[tid] = gt[b * 126 + tid];
  if (tid >= 128 && tid < 130) {   // second wave: per-hand area/denominator
    const int h = tid - 128;
    const float* g = gt + b * 126 + h * 63;
    float mnx = g[0], mxx = g[0], mny = g[1], mxy = g[1];
    float nv = (g[2] > 0.0f) ? 1.0f : 0.0f;
    for (int j = 1; j < 21; ++j) {
      float x = g[j * 3], y = g[j * 3 + 1];
      mnx = fminf(mnx, x); mxx = fmaxf(mxx, x);
      mny = fminf(mny, y); mxy = fmaxf(mxy, y);
      nv += (g[j * 3 + 2] > 0.0f) ? 1.0f : 0.0f;
    }
    const float area = (mxx - mnx) * (mxy - mny);
    const float s2 = fmaxf(area, 1.0f);
    sden[h] = (2.0f * s2) * 0.01f;   // 2*s2*k2, k2 -> 0.01f in f32
    snv[h] = fmaxf(nv, 1.0f);
  }
  if (tid >= 130 && tid < 132) sht[tid - 130] = ht[b * 2 + (tid - 130)];
  __syncthreads();

  const int a = ab * 256 + tid;
  const int p = a % 12;
  const int kc = a / 12;
  const float shx = 4.0f * (float)(kc & 63);
  const float shy = 4.0f * (float)(kc >> 6);
  float cx, cy; ref_center(cx, cy);

  bool inside = true;
  float q0[8], q1[8];
  #pragma unroll
  for (int j = 0; j < 16; ++j) {     // numpy pairwise tree, n=21
    float2 an = anchor_pt(p, j, cx, cy, shx, shy);
    inside = inside && (an.x >= 0.0f) && (an.y >= 0.0f) &&
                       (an.x < 256.0f) && (an.y < 256.0f);
    float t0, t1;
    OKS_TERM(0, j, an.x, an.y, t0);
    OKS_TERM(1, j, an.x, an.y, t1);
    if (j < 8) { q0[j] = t0; q1[j] = t1; }
    else       { q0[j - 8] += t0; q1[j - 8] += t1; }
  }
  float s0 = ((q0[0] + q0[1]) + (q0[2] + q0[3])) + ((q0[4] + q0[5]) + (q0[6] + q0[7]));
  float s1 = ((q1[0] + q1[1]) + (q1[2] + q1[3])) + ((q1[4] + q1[5]) + (q1[6] + q1[7]));
  #pragma unroll
  for (int j = 16; j < 21; ++j) {    // sequential tail, numpy order
    float2 an = anchor_pt(p, j, cx, cy, shx, shy);
    inside = inside && (an.x >= 0.0f) && (an.y >= 0.0f) &&
                       (an.x < 256.0f) && (an.y < 256.0f);
    float t0, t1;
    OKS_TERM(0, j, an.x, an.y, t0);
    OKS_TERM(1, j, an.x, an.y, t1);
    s0 += t0; s1 += t1;
  }

  const float sim0 = s0 / snv[0];
  const float sim1 = s1 / snv[1];
  const int am = (sim1 > sim0) ? 1 : 0;   // argmax: first index wins ties
  const float mx = fmaxf(sim0, sim1);
  const bool pos = mx > 0.5f;
  const bool right = (am == 0) && pos && (sht[0] == 1) && inside;
  const bool left  = (am == 1) && pos && (sht[1] == 1) && inside;
  const bool neg   = (!right) && (!left) && inside;

  const size_t pidx = (size_t)b * NA + (size_t)a;
  float* lab = ol + pidx * 3;
  if (inside) {
    lab[0] = left ? 1.0f : 0.0f;
    lab[1] = neg  ? 1.0f : 0.0f;
    lab[2] = right ? 1.0f : 0.0f;
  } else {
    lab[0] = -1.0f; lab[1] = -1.0f; lab[2] = -1.0f;
  }

  const bool has = right || left;
  const int hoff = right ? 0 : 63;
  float2* op = reinterpret_cast<float2*>(oo) + pidx * 21;
  #pragma unroll
  for (int j = 0; j < 21; ++j) {
    float2 an = anchor_pt(p, j, cx, cy, shx, shy);
    const float tx = has ? sgt[hoff + j * 3]     : 0.0f;
    const float ty = has ? sgt[hoff + j * 3 + 1] : 0.0f;
    op[j] = make_float2(inside ? (tx - an.x) : 0.0f,
                        inside ? (ty - an.y) : 0.0f);
  }
}

extern "C" void kernel_launch(void* const* d_in, const int* in_sizes, int n_in,
                              void* d_out, int out_size, void* d_ws, size_t ws_size,
                              hipStream_t stream) {
  (void)in_sizes; (void)n_in; (void)d_ws; (void)ws_size; (void)out_size;
  const float* gt = (const float*)d_in[0];   // (16,42,3) f32
  const int* ht = (const int*)d_in[1];       // (16,2) i32
  float* out = (float*)d_out;
  float* out_anchors = out;                                   // NA*42
  float* out_inside  = out + (size_t)NA * 42;                 // NA
  float* out_labels  = out + (size_t)NA * 43;                 // NB*NA*3
  float* out_offsets = out_labels + (size_t)NB * NA * 3;      // NB*NA*42

  hipLaunchKernelGGL(k_anchors, dim3(ABLOCKS), dim3(256), 0, stream,
                     out_anchors, out_inside);
  hipLaunchKernelGGL(k_targets, dim3(NB * ABLOCKS), dim3(256), 0, stream,
                     gt, ht, out_labels, out_offsets);
}

// Round 3
// 185.265 us; speedup vs baseline: 1.3266x; 1.3266x over previous
//
#include <hip/hip_runtime.h>
#include <math.h>

#define NA 49152      // 64*64*12 anchors
#define NB 16
#define ABLOCKS 192   // NA / 256
#define LSTR 43       // LDS words per anchor: 42 payload + 1 pad (odd -> conflict-free fill)
#define EPS 1e-3f     // decision-boundary guard; fast-sim error <= ~1e-4

__constant__ float RP[21][2] = {
  {213.33335876464844f, 124.50563049316406f},
  {190.504638671875f,   115.11840057373047f},
  {169.9791717529297f,  101.77180480957031f},
  {146.72341918945312f, 96.25749206542969f},
  {128.86770629882812f, 87.2344970703125f},
  {150.34292602539062f, 101.61070251464844f},
  {119.29926300048828f, 98.73982238769531f},
  {100.03463745117188f, 99.74459838867188f},
  {82.62400817871094f,  101.2509536743164f},
  {148.91049194335938f, 112.71517181396484f},
  {114.37303161621094f, 113.20121002197266f},
  {91.90096282958984f,  116.49812316894531f},
  {74.75020599365234f,  119.37875366210938f},
  {149.59658813476562f, 124.09295654296875f},
  {119.72419738769531f, 126.36898040771484f},
  {99.59107208251953f,  129.40196228027344f},
  {82.82524108886719f,  131.584228515625f},
  {154.55911254882812f, 135.07681274414062f},
  {133.8833770751953f,  140.85983276367188f},
  {120.45906066894531f, 145.40306091308594f},
  {106.21541595458984f, 150.072265625f}
};

// numpy pairwise-sum (n=21) replica for REF_POSE.mean(axis=0)
__device__ __forceinline__ void ref_center(float& cx, float& cy) {
  #pragma clang fp contract(off)
  float rx[8], ry[8];
  #pragma unroll
  for (int j = 0; j < 8; ++j) {
    rx[j] = RP[j][0] + RP[j + 8][0];
    ry[j] = RP[j][1] + RP[j + 8][1];
  }
  float sx = ((rx[0] + rx[1]) + (rx[2] + rx[3])) + ((rx[4] + rx[5]) + (rx[6] + rx[7]));
  float sy = ((ry[0] + ry[1]) + (ry[2] + ry[3])) + ((ry[4] + ry[5]) + (ry[6] + ry[7]));
  #pragma unroll
  for (int j = 16; j < 21; ++j) { sx += RP[j][0]; sy += RP[j][1]; }
  cx = sx / 21.0f;
  cy = sy / 21.0f;
}

// Rotations by 0/90/180/270 are exactly negate/swap under f32.
__device__ __forceinline__ float2 anchor_pt(int p, int j, float cx, float cy,
                                            float shx, float shy) {
  #pragma clang fp contract(off)
  const int si = p >> 2, oi = p & 3;
  const float s = (si == 0) ? 0.25f : (si == 1 ? 0.5f : 1.0f);
  const float dx = s * (RP[j][0] - cx);
  const float dy = s * (RP[j][1] - cy);
  const float rx = (oi == 0) ? dx : (oi == 1 ? -dy : (oi == 2 ? -dx : dy));
  const float ry = (oi == 0) ? dy : (oi == 1 ? dx : (oi == 2 ? -dy : -dx));
  return make_float2((cx + rx) + shx, (cy + ry) + shy);
}

__global__ __launch_bounds__(256) void k_anchors(float* __restrict__ oa,
                                                 float* __restrict__ oinside) {
  __shared__ float sbuf[4 * 64 * LSTR];
  const int tid = threadIdx.x, lane = tid & 63, w = tid >> 6;
  float* wbuf = sbuf + w * (64 * LSTR);
  const int a = blockIdx.x * 256 + tid;
  float cx, cy; ref_center(cx, cy);
  const int p = a % 12;
  const int kc = a / 12;
  const float shx = 4.0f * (float)(kc & 63);
  const float shy = 4.0f * (float)(kc >> 6);
  bool inside = true;
  #pragma unroll
  for (int j = 0; j < 21; ++j) {
    float2 an = anchor_pt(p, j, cx, cy, shx, shy);
    inside = inside && (an.x >= 0.0f) && (an.y >= 0.0f) &&
                       (an.x < 256.0f) && (an.y < 256.0f);
    wbuf[lane * LSTR + 2 * j]     = an.x;
    wbuf[lane * LSTR + 2 * j + 1] = an.y;
  }
  oinside[a] = inside ? 1.0f : 0.0f;
  __syncthreads();
  // coalesced drain: 21 x 512B contiguous float2 stores per wave
  const int a0 = blockIdx.x * 256 + w * 64;
  float2* op = reinterpret_cast<float2*>(oa) + (size_t)a0 * 21;
  #pragma unroll
  for (int i = 0; i < 21; ++i) {
    const int f2 = i * 64 + lane;
    const int aloc = f2 / 21;
    const int j = f2 - aloc * 21;
    op[f2] = make_float2(wbuf[aloc * LSTR + 2 * j],
                         wbuf[aloc * LSTR + 2 * j + 1]);
  }
}

__global__ __launch_bounds__(256) void k_targets(const float* __restrict__ gt,
                                                 const int* __restrict__ ht,
                                                 float* __restrict__ ol,
                                                 float* __restrict__ oo) {
  __shared__ float sbuf[4 * 64 * LSTR];   // per-wave anchor staging
  __shared__ int shsel[256];              // per-anchor decision code
  __shared__ float sgt[126];
  __shared__ float sden[2];
  __shared__ float srden[2];
  __shared__ float snv[2];
  __shared__ int sht[2];
  const int tid = threadIdx.x, lane = tid & 63, w = tid >> 6;
  float* wbuf = sbuf + w * (64 * LSTR);
  const int b = blockIdx.x / ABLOCKS;
  const int ab = blockIdx.x % ABLOCKS;

  if (tid < 126) sgt[tid] = gt[b * 126 + tid];
  if (tid >= 128 && tid < 130) {   // second wave: per-hand area/denominator
    const int h = tid - 128;
    const float* g = gt + b * 126 + h * 63;
    float mnx = g[0], mxx = g[0], mny = g[1], mxy = g[1];
    float nv = (g[2] > 0.0f) ? 1.0f : 0.0f;
    for (int j = 1; j < 21; ++j) {
      float x = g[j * 3], y = g[j * 3 + 1];
      mnx = fminf(mnx, x); mxx = fmaxf(mxx, x);
      mny = fminf(mny, y); mxy = fmaxf(mxy, y);
      nv += (g[j * 3 + 2] > 0.0f) ? 1.0f : 0.0f;
    }
    const float area = (mxx - mnx) * (mxy - mny);
    const float s2 = fmaxf(area, 1.0f);
    const float den = (2.0f * s2) * 0.01f;   // 2*s2*k2, k2 -> 0.01f in f32
    sden[h] = den;
    srden[h] = -1.0f / den;
    snv[h] = fmaxf(nv, 1.0f);
  }
  if (tid >= 130 && tid < 132) sht[tid - 130] = ht[b * 2 + (tid - 130)];
  __syncthreads();

  const int a = ab * 256 + tid;
  const int p = a % 12;
  const int kc = a / 12;
  const float shx = 4.0f * (float)(kc & 63);
  const float shy = 4.0f * (float)(kc >> 6);
  float cx, cy; ref_center(cx, cy);

  // ---- fast path: fill LDS with anchors, accumulate __expf-based sims ----
  const float rd0 = srden[0], rd1 = srden[1];
  bool inside = true;
  float s0f = 0.0f, s1f = 0.0f;
  #pragma unroll
  for (int j = 0; j < 21; ++j) {
    float2 an = anchor_pt(p, j, cx, cy, shx, shy);
    inside = inside && (an.x >= 0.0f) && (an.y >= 0.0f) &&
                       (an.x < 256.0f) && (an.y < 256.0f);
    wbuf[lane * LSTR + 2 * j]     = an.x;
    wbuf[lane * LSTR + 2 * j + 1] = an.y;
    float dx0 = an.x - sgt[j * 3],      dy0 = an.y - sgt[j * 3 + 1];
    float dx1 = an.x - sgt[63 + j * 3], dy1 = an.y - sgt[63 + j * 3 + 1];
    float v0 = (sgt[j * 3 + 2] > 0.0f) ? 1.0f : 0.0f;
    float v1 = (sgt[63 + j * 3 + 2] > 0.0f) ? 1.0f : 0.0f;
    s0f += __expf((dx0 * dx0 + dy0 * dy0) * rd0) * v0;
    s1f += __expf((dx1 * dx1 + dy1 * dy1) * rd1) * v1;
  }
  float sim0 = s0f / snv[0];
  float sim1 = s1f / snv[1];
  const float mxf = fmaxf(sim0, sim1);
  const bool need_exact = (fabsf(mxf - 0.5f) < EPS) ||
                          ((mxf > 0.5f - EPS) && (fabsf(sim0 - sim1) < EPS));

  if (need_exact) {
    // ---- exact fallback: bit-identical to round-1 (double exp, numpy tree) ----
    #pragma clang fp contract(off)
    float q0[8], q1[8];
    #pragma unroll
    for (int j = 0; j < 16; ++j) {
      float ax = wbuf[lane * LSTR + 2 * j], ay = wbuf[lane * LSTR + 2 * j + 1];
      float dx0 = ax - sgt[j * 3], dy0 = ay - sgt[j * 3 + 1];
      float d20 = dx0 * dx0 + dy0 * dy0;
      float vv0 = (sgt[j * 3 + 2] > 0.0f) ? 1.0f : 0.0f;
      float t0 = (float)::exp((double)(-d20 / sden[0])) * vv0;
      float dx1 = ax - sgt[63 + j * 3], dy1 = ay - sgt[63 + j * 3 + 1];
      float d21 = dx1 * dx1 + dy1 * dy1;
      float vv1 = (sgt[63 + j * 3 + 2] > 0.0f) ? 1.0f : 0.0f;
      float t1 = (float)::exp((double)(-d21 / sden[1])) * vv1;
      if (j < 8) { q0[j] = t0; q1[j] = t1; }
      else       { q0[j - 8] += t0; q1[j - 8] += t1; }
    }
    float s0 = ((q0[0] + q0[1]) + (q0[2] + q0[3])) + ((q0[4] + q0[5]) + (q0[6] + q0[7]));
    float s1 = ((q1[0] + q1[1]) + (q1[2] + q1[3])) + ((q1[4] + q1[5]) + (q1[6] + q1[7]));
    #pragma unroll
    for (int j = 16; j < 21; ++j) {
      float ax = wbuf[lane * LSTR + 2 * j], ay = wbuf[lane * LSTR + 2 * j + 1];
      float dx0 = ax - sgt[j * 3], dy0 = ay - sgt[j * 3 + 1];
      float d20 = dx0 * dx0 + dy0 * dy0;
      float vv0 = (sgt[j * 3 + 2] > 0.0f) ? 1.0f : 0.0f;
      s0 += (float)::exp((double)(-d20 / sden[0])) * vv0;
      float dx1 = ax - sgt[63 + j * 3], dy1 = ay - sgt[63 + j * 3 + 1];
      float d21 = dx1 * dx1 + dy1 * dy1;
      float vv1 = (sgt[63 + j * 3 + 2] > 0.0f) ? 1.0f : 0.0f;
      s1 += (float)::exp((double)(-d21 / sden[1])) * vv1;
    }
    sim0 = s0 / snv[0];
    sim1 = s1 / snv[1];
  }

  const int am = (sim1 > sim0) ? 1 : 0;   // argmax: first index wins ties
  const float mx = fmaxf(sim0, sim1);
  const bool pos = mx > 0.5f;
  const bool right = (am == 0) && pos && (sht[0] == 1) && inside;
  const bool left  = (am == 1) && pos && (sht[1] == 1) && inside;
  const bool neg   = (!right) && (!left) && inside;

  int c;            // -1 outside, 0 neg, 1 right, 2 left
  if (!inside)      c = -1;
  else if (right)   c = 1;
  else if (left)    c = 2;
  else              c = 0;
  shsel[tid] = c;

  const size_t pidx = (size_t)b * NA + (size_t)a;
  float* lab = ol + pidx * 3;
  if (inside) {
    lab[0] = left ? 1.0f : 0.0f;
    lab[1] = neg  ? 1.0f : 0.0f;
    lab[2] = right ? 1.0f : 0.0f;
  } else {
    lab[0] = -1.0f; lab[1] = -1.0f; lab[2] = -1.0f;
  }

  __syncthreads();
  // ---- coalesced offsets drain: 21 x 512B contiguous float2 stores per wave ----
  const int a0 = ab * 256 + w * 64;
  float2* op = reinterpret_cast<float2*>(oo) + ((size_t)b * NA + a0) * 21;
  #pragma unroll
  for (int i = 0; i < 21; ++i) {
    #pragma clang fp contract(off)
    const int f2 = i * 64 + lane;
    const int aloc = f2 / 21;
    const int j = f2 - aloc * 21;
    const float anx = wbuf[aloc * LSTR + 2 * j];
    const float any = wbuf[aloc * LSTR + 2 * j + 1];
    const int cc = shsel[w * 64 + aloc];
    const bool has = (cc == 1) || (cc == 2);
    const int hoff = (cc == 2) ? 63 : 0;
    const float tx = has ? sgt[hoff + j * 3]     : 0.0f;
    const float ty = has ? sgt[hoff + j * 3 + 1] : 0.0f;
    const float ox = (cc >= 0) ? (tx - anx) : 0.0f;
    const float oy = (cc >= 0) ? (ty - any) : 0.0f;
    op[f2] = make_float2(ox, oy);
  }
}

extern "C" void kernel_launch(void* const* d_in, const int* in_sizes, int n_in,
                              void* d_out, int out_size, void* d_ws, size_t ws_size,
                              hipStream_t stream) {
  (void)in_sizes; (void)n_in; (void)d_ws; (void)ws_size; (void)out_size;
  const float* gt = (const float*)d_in[0];   // (16,42,3) f32
  const int* ht = (const int*)d_in[1];       // (16,2) i32
  float* out = (float*)d_out;
  float* out_anchors = out;                                   // NA*42
  float* out_inside  = out + (size_t)NA * 42;                 // NA
  float* out_labels  = out + (size_t)NA * 43;                 // NB*NA*3
  float* out_offsets = out_labels + (size_t)NB * NA * 3;      // NB*NA*42

  hipLaunchKernelGGL(k_anchors, dim3(ABLOCKS), dim3(256), 0, stream,
                     out_anchors, out_inside);
  hipLaunchKernelGGL(k_targets, dim3(NB * ABLOCKS), dim3(256), 0, stream,
                     gt, ht, out_labels, out_offsets);
}

// Round 4
// 178.499 us; speedup vs baseline: 1.3769x; 1.0379x over previous
//
#include <hip/hip_runtime.h>
#include <math.h>

#define NA 49152      // 64*64*12 anchors
#define NB 16
#define ABLOCKS 192   // NA / 256
#define EPS 1e-3f     // decision-boundary guard; fast-sim error <= ~1e-4

__constant__ float RP[21][2] = {
  {213.33335876464844f, 124.50563049316406f},
  {190.504638671875f,   115.11840057373047f},
  {169.9791717529297f,  101.77180480957031f},
  {146.72341918945312f, 96.25749206542969f},
  {128.86770629882812f, 87.2344970703125f},
  {150.34292602539062f, 101.61070251464844f},
  {119.29926300048828f, 98.73982238769531f},
  {100.03463745117188f, 99.74459838867188f},
  {82.62400817871094f,  101.2509536743164f},
  {148.91049194335938f, 112.71517181396484f},
  {114.37303161621094f, 113.20121002197266f},
  {91.90096282958984f,  116.49812316894531f},
  {74.75020599365234f,  119.37875366210938f},
  {149.59658813476562f, 124.09295654296875f},
  {119.72419738769531f, 126.36898040771484f},
  {99.59107208251953f,  129.40196228027344f},
  {82.82524108886719f,  131.584228515625f},
  {154.55911254882812f, 135.07681274414062f},
  {133.8833770751953f,  140.85983276367188f},
  {120.45906066894531f, 145.40306091308594f},
  {106.21541595458984f, 150.072265625f}
};

// numpy pairwise-sum (n=21) replica for REF_POSE.mean(axis=0)
__device__ __forceinline__ void ref_center(float& cx, float& cy) {
  #pragma clang fp contract(off)
  float rx[8], ry[8];
  #pragma unroll
  for (int j = 0; j < 8; ++j) {
    rx[j] = RP[j][0] + RP[j + 8][0];
    ry[j] = RP[j][1] + RP[j + 8][1];
  }
  float sx = ((rx[0] + rx[1]) + (rx[2] + rx[3])) + ((rx[4] + rx[5]) + (rx[6] + rx[7]));
  float sy = ((ry[0] + ry[1]) + (ry[2] + ry[3])) + ((ry[4] + ry[5]) + (ry[6] + ry[7]));
  #pragma unroll
  for (int j = 16; j < 21; ++j) { sx += RP[j][0]; sy += RP[j][1]; }
  cx = sx / 21.0f;
  cy = sy / 21.0f;
}

// base pose (block-invariant): c + s*(RP-c)@R. Rotations by 0/90/180/270 are
// exactly negate/swap under f32. Anchor = base + shift (same association as ref).
__device__ __forceinline__ float2 base_pt(int p, int j, float cx, float cy) {
  #pragma clang fp contract(off)
  const int si = p >> 2, oi = p & 3;
  const float s = (si == 0) ? 0.25f : (si == 1 ? 0.5f : 1.0f);
  const float dx = s * (RP[j][0] - cx);
  const float dy = s * (RP[j][1] - cy);
  const float rx = (oi == 0) ? dx : (oi == 1 ? -dy : (oi == 2 ? -dx : dy));
  const float ry = (oi == 0) ? dy : (oi == 1 ? dx : (oi == 2 ? -dy : -dx));
  return make_float2(cx + rx, cy + ry);
}

// decode flat float2-index f2 (anchor-local, kpt) -> anchor coords from base table
__device__ __forceinline__ void dec_anchor(int f2, int a0, const float2* sb2,
                                           float& anx, float& any,
                                           int& aloc, int& j) {
  #pragma clang fp contract(off)
  aloc = f2 / 21;
  j = f2 - aloc * 21;
  const int a = a0 + aloc;
  const int p = a % 12;
  const int kc = a / 12;
  const float shx = 4.0f * (float)(kc & 63);
  const float shy = 4.0f * (float)(kc >> 6);
  const float2 bpv = sb2[p * 21 + j];
  anx = bpv.x + shx;
  any = bpv.y + shy;
}

__device__ __forceinline__ float4 off_quad(int idx, int a0, const float2* sb2,
                                           const float* sgt, const int* shsel) {
  #pragma clang fp contract(off)
  float r[4];
  #pragma unroll
  for (int h = 0; h < 2; ++h) {
    float anx, any; int aloc, j;
    dec_anchor(idx * 2 + h, a0, sb2, anx, any, aloc, j);
    const int cc = shsel[aloc];
    const bool has = (cc == 1) || (cc == 2);
    const int hoff = (cc == 2) ? 63 : 0;
    const float tx = has ? sgt[hoff + j * 3] : 0.0f;
    const float ty = has ? sgt[hoff + j * 3 + 1] : 0.0f;
    r[h * 2]     = (cc >= 0) ? (tx - anx) : 0.0f;
    r[h * 2 + 1] = (cc >= 0) ? (ty - any) : 0.0f;
  }
  return make_float4(r[0], r[1], r[2], r[3]);
}

__device__ __forceinline__ float4 anc_quad(int idx, int a0, const float2* sb2) {
  float r[4];
  #pragma unroll
  for (int h = 0; h < 2; ++h) {
    float anx, any; int aloc, j;
    dec_anchor(idx * 2 + h, a0, sb2, anx, any, aloc, j);
    r[h * 2] = anx;
    r[h * 2 + 1] = any;
  }
  return make_float4(r[0], r[1], r[2], r[3]);
}

__global__ __launch_bounds__(256) void k_all(const float* __restrict__ gt,
                                             const int* __restrict__ ht,
                                             float* __restrict__ oa,
                                             float* __restrict__ oins,
                                             float* __restrict__ ol,
                                             float* __restrict__ oo) {
  __shared__ float2 sb2[252];     // base poses [p][j]
  __shared__ float sgt[126];
  __shared__ float sden[2], srden[2], snv[2];
  __shared__ int sht[2];
  __shared__ int shsel[256];      // per-anchor decision code
  __shared__ float sins[256];     // per-anchor inside flag

  const int tid = threadIdx.x;
  const int b = blockIdx.x / ABLOCKS;
  const int ab = blockIdx.x % ABLOCKS;
  const int a0 = ab * 256;

  if (tid < 126) sgt[tid] = gt[b * 126 + tid];
  if (tid < 252) {
    float cx, cy; ref_center(cx, cy);
    const int p = tid / 21;
    const int j = tid - p * 21;
    sb2[tid] = base_pt(p, j, cx, cy);
  }
  if (tid == 252 || tid == 253) {   // per-hand area/denominator
    const int h = tid - 252;
    const float* g = gt + b * 126 + h * 63;
    float mnx = g[0], mxx = g[0], mny = g[1], mxy = g[1];
    float nv = (g[2] > 0.0f) ? 1.0f : 0.0f;
    for (int j = 1; j < 21; ++j) {
      float x = g[j * 3], y = g[j * 3 + 1];
      mnx = fminf(mnx, x); mxx = fmaxf(mxx, x);
      mny = fminf(mny, y); mxy = fmaxf(mxy, y);
      nv += (g[j * 3 + 2] > 0.0f) ? 1.0f : 0.0f;
    }
    const float area = (mxx - mnx) * (mxy - mny);
    const float s2 = fmaxf(area, 1.0f);
    const float den = (2.0f * s2) * 0.01f;   // 2*s2*k2, k2 -> 0.01f in f32
    sden[h] = den;
    srden[h] = -1.0f / den;
    snv[h] = fmaxf(nv, 1.0f);
  }
  if (tid == 254 || tid == 255) sht[tid - 254] = ht[b * 2 + (tid - 254)];
  __syncthreads();

  const int a = a0 + tid;
  const int p = a % 12;
  const int kc = a / 12;
  const float shx = 4.0f * (float)(kc & 63);
  const float shy = 4.0f * (float)(kc >> 6);
  const float2* bp = sb2 + p * 21;

  // ---- fast path: __expf-based sims ----
  const float rd0 = srden[0], rd1 = srden[1];
  bool inside = true;
  float s0f = 0.0f, s1f = 0.0f;
  #pragma unroll
  for (int j = 0; j < 21; ++j) {
    #pragma clang fp contract(off)
    const float anx = bp[j].x + shx;
    const float any = bp[j].y + shy;
    inside = inside && (anx >= 0.0f) && (any >= 0.0f) &&
                       (anx < 256.0f) && (any < 256.0f);
    const float dx0 = anx - sgt[j * 3],      dy0 = any - sgt[j * 3 + 1];
    const float dx1 = anx - sgt[63 + j * 3], dy1 = any - sgt[63 + j * 3 + 1];
    const float v0 = (sgt[j * 3 + 2] > 0.0f) ? 1.0f : 0.0f;
    const float v1 = (sgt[63 + j * 3 + 2] > 0.0f) ? 1.0f : 0.0f;
    s0f += __expf((dx0 * dx0 + dy0 * dy0) * rd0) * v0;
    s1f += __expf((dx1 * dx1 + dy1 * dy1) * rd1) * v1;
  }
  float sim0 = s0f / snv[0];
  float sim1 = s1f / snv[1];
  const float mxf = fmaxf(sim0, sim1);
  const bool need_exact = (fabsf(mxf - 0.5f) < EPS) ||
                          ((mxf > 0.5f - EPS) && (fabsf(sim0 - sim1) < EPS));

  if (need_exact) {
    // ---- exact fallback: bit-identical to round-1 (double exp, numpy tree) ----
    #pragma clang fp contract(off)
    float q0[8], q1[8];
    #pragma unroll
    for (int j = 0; j < 16; ++j) {
      const float ax = bp[j].x + shx, ay = bp[j].y + shy;
      float dx0 = ax - sgt[j * 3], dy0 = ay - sgt[j * 3 + 1];
      float d20 = dx0 * dx0 + dy0 * dy0;
      float vv0 = (sgt[j * 3 + 2] > 0.0f) ? 1.0f : 0.0f;
      float t0 = (float)::exp((double)(-d20 / sden[0])) * vv0;
      float dx1 = ax - sgt[63 + j * 3], dy1 = ay - sgt[63 + j * 3 + 1];
      float d21 = dx1 * dx1 + dy1 * dy1;
      float vv1 = (sgt[63 + j * 3 + 2] > 0.0f) ? 1.0f : 0.0f;
      float t1 = (float)::exp((double)(-d21 / sden[1])) * vv1;
      if (j < 8) { q0[j] = t0; q1[j] = t1; }
      else       { q0[j - 8] += t0; q1[j - 8] += t1; }
    }
    float s0 = ((q0[0] + q0[1]) + (q0[2] + q0[3])) + ((q0[4] + q0[5]) + (q0[6] + q0[7]));
    float s1 = ((q1[0] + q1[1]) + (q1[2] + q1[3])) + ((q1[4] + q1[5]) + (q1[6] + q1[7]));
    #pragma unroll
    for (int j = 16; j < 21; ++j) {
      const float ax = bp[j].x + shx, ay = bp[j].y + shy;
      float dx0 = ax - sgt[j * 3], dy0 = ay - sgt[j * 3 + 1];
      float d20 = dx0 * dx0 + dy0 * dy0;
      float vv0 = (sgt[j * 3 + 2] > 0.0f) ? 1.0f : 0.0f;
      s0 += (float)::exp((double)(-d20 / sden[0])) * vv0;
      float dx1 = ax - sgt[63 + j * 3], dy1 = ay - sgt[63 + j * 3 + 1];
      float d21 = dx1 * dx1 + dy1 * dy1;
      float vv1 = (sgt[63 + j * 3 + 2] > 0.0f) ? 1.0f : 0.0f;
      s1 += (float)::exp((double)(-d21 / sden[1])) * vv1;
    }
    sim0 = s0 / snv[0];
    sim1 = s1 / snv[1];
  }

  const int am = (sim1 > sim0) ? 1 : 0;   // argmax: first index wins ties
  const float mx = fmaxf(sim0, sim1);
  const bool pos = mx > 0.5f;
  const bool right = (am == 0) && pos && (sht[0] == 1) && inside;
  const bool left  = (am == 1) && pos && (sht[1] == 1) && inside;

  int c;            // -1 outside, 0 neg, 1 right, 2 left
  if (!inside)      c = -1;
  else if (right)   c = 1;
  else if (left)    c = 2;
  else              c = 0;
  shsel[tid] = c;
  sins[tid] = inside ? 1.0f : 0.0f;
  __syncthreads();

  // ---- labels drain: 192 float4 per block, fully coalesced ----
  if (tid < 192) {
    float4* lf4 = reinterpret_cast<float4*>(ol + ((size_t)b * NA + a0) * 3);
    float r[4];
    #pragma unroll
    for (int k = 0; k < 4; ++k) {
      const int q = tid * 4 + k;
      const int al = q / 3;
      const int rr = q - al * 3;
      const int cc = shsel[al];
      float v;
      if (cc < 0)       v = -1.0f;
      else if (rr == 0) v = (cc == 2) ? 1.0f : 0.0f;   // left
      else if (rr == 1) v = (cc == 0) ? 1.0f : 0.0f;   // neg
      else              v = (cc == 1) ? 1.0f : 0.0f;   // right
      r[k] = v;
    }
    lf4[tid] = make_float4(r[0], r[1], r[2], r[3]);
  }

  // ---- offsets drain: 2688 float4 per block, fully coalesced ----
  {
    float4* of4 = reinterpret_cast<float4*>(oo + ((size_t)b * NA + a0) * 42);
    #pragma unroll
    for (int i = 0; i < 10; ++i) {
      const int idx = i * 256 + tid;
      of4[idx] = off_quad(idx, a0, sb2, sgt, shsel);
    }
    if (tid < 128) {
      const int idx = 2560 + tid;
      of4[idx] = off_quad(idx, a0, sb2, sgt, shsel);
    }
  }

  // ---- anchors + inside drains (b == 0 blocks only) ----
  if (b == 0) {
    float4* af4 = reinterpret_cast<float4*>(oa + (size_t)a0 * 42);
    #pragma unroll
    for (int i = 0; i < 10; ++i) {
      const int idx = i * 256 + tid;
      af4[idx] = anc_quad(idx, a0, sb2);
    }
    if (tid < 128) {
      const int idx = 2560 + tid;
      af4[idx] = anc_quad(idx, a0, sb2);
    }
    if (tid < 64) {
      float4* if4 = reinterpret_cast<float4*>(oins + a0);
      if4[tid] = make_float4(sins[tid * 4], sins[tid * 4 + 1],
                             sins[tid * 4 + 2], sins[tid * 4 + 3]);
    }
  }
}

extern "C" void kernel_launch(void* const* d_in, const int* in_sizes, int n_in,
                              void* d_out, int out_size, void* d_ws, size_t ws_size,
                              hipStream_t stream) {
  (void)in_sizes; (void)n_in; (void)d_ws; (void)ws_size; (void)out_size;
  const float* gt = (const float*)d_in[0];   // (16,42,3) f32
  const int* ht = (const int*)d_in[1];       // (16,2) i32
  float* out = (float*)d_out;
  float* out_anchors = out;                                   // NA*42
  float* out_inside  = out + (size_t)NA * 42;                 // NA
  float* out_labels  = out + (size_t)NA * 43;                 // NB*NA*3
  float* out_offsets = out_labels + (size_t)NB * NA * 3;      // NB*NA*42

  hipLaunchKernelGGL(k_all, dim3(NB * ABLOCKS), dim3(256), 0, stream,
                     gt, ht, out_anchors, out_inside, out_labels, out_offsets);
}